// Round 1
// baseline (1684.657 us; speedup 1.0000x reference)
//
#include <hip/hip_runtime.h>

namespace {

constexpr int T     = 1024;
constexpr int HDIM  = 2880;
constexpr int DDIM  = 2880;
constexpr int NE    = 8;
constexpr int TWO_D = 5760;
constexpr float ALPHA = 1.702f;
constexpr float LIMIT = 7.0f;

// LDS row stride (elements) for 32-K tiles: 32 + 8 pad -> 80 B rows, 16B-aligned,
// bank pattern (20 words) gives <=2-way conflicts on ds_read_b128 (free per m136).
constexpr int LDSS = 40;

typedef __attribute__((ext_vector_type(8))) short bf16x8;          // MFMA A/B frag (4 VGPR)
typedef __attribute__((ext_vector_type(4))) unsigned short u16x4;  // 8B LDS store
typedef __attribute__((ext_vector_type(4))) float f32x4;           // MFMA C/D frag

__device__ __forceinline__ unsigned short f2bf(float f) {
  union { float f; unsigned u; } x; x.f = f;
  unsigned u = x.u;
  u += 0x7fffu + ((u >> 16) & 1u);   // RNE
  return (unsigned short)(u >> 16);
}

} // namespace

// ---------------------------------------------------------------------------
// Y[t,h] = sum_e rw[t,e] * b2[e,h]   (bias pre-fill; overwrites poison)
// grid (45, 1024), block 64
__global__ void init_bias_kernel(const float* __restrict__ RW,
                                 const float* __restrict__ B2,
                                 float* __restrict__ Y) {
  int h = blockIdx.x * 64 + threadIdx.x;
  int t = blockIdx.y;
  float s = 0.f;
#pragma unroll
  for (int e = 0; e < NE; ++e) s += RW[t * NE + e] * B2[e * HDIM + h];
  Y[(size_t)t * HDIM + h] = s;
}

// ---------------------------------------------------------------------------
// GEMM1 + bias + glu activation + rw scaling -> A' (E,T,D) bf16 in ws.
// grid (8 m, 45 n, 8 e), block 256 (4 waves), tile 128x128x32.
__global__ __launch_bounds__(256) void gemm1_act_kernel(
    const float* __restrict__ X,    // (T,H)
    const float* __restrict__ W1,   // (E,H,2D)
    const float* __restrict__ B1,   // (E,2D)
    const float* __restrict__ RW,   // (T,E)
    unsigned short* __restrict__ A) // (E,T,D) bf16
{
  __shared__ __align__(16) unsigned short lA[128 * LDSS];
  __shared__ __align__(16) unsigned short lB[128 * LDSS];

  const int tid = threadIdx.x;
  const int m0 = blockIdx.x * 128;
  const int n0 = blockIdx.y * 128;       // weight-column base (gate/up interleaved)
  const int e  = blockIdx.z;
  const float* Wp = W1 + (size_t)e * HDIM * TWO_D;

  f32x4 acc[4][4];
#pragma unroll
  for (int i = 0; i < 4; ++i)
#pragma unroll
    for (int j = 0; j < 4; ++j) acc[i][j] = (f32x4)0.f;

  const int w    = tid >> 6;
  const int lane = tid & 63;
  const int wm   = w & 1, wn = w >> 1;
  const int r    = lane & 15, q = lane >> 4;

  // staging assignments
  const int sa_m = tid >> 3;   // 0..31  (A rows, x4 iters)
  const int sa_q = tid & 7;    // k-chunk of 4
  const int sb_n = tid & 127;  // B column
  const int sb_k = tid >> 7;   // 0..1 (k-chunk of 8, x2 iters)

  for (int kt = 0; kt < HDIM / 32; ++kt) {
    const int k0g = kt * 32;

    // ---- stage A (X fp32 -> bf16), rows k-contiguous
#pragma unroll
    for (int it = 0; it < 4; ++it) {
      int m = sa_m + it * 32;
      const f32x4 v = *(const f32x4*)(X + (size_t)(m0 + m) * HDIM + k0g + sa_q * 4);
      u16x4 pv = { f2bf(v.x), f2bf(v.y), f2bf(v.z), f2bf(v.w) };
      *(u16x4*)(&lA[m * LDSS + sa_q * 4]) = pv;
    }

    // ---- stage B (W1 fp32, K-major in HBM) -> LDS [n][k] (transposed), bf16
#pragma unroll
    for (int it = 0; it < 2; ++it) {
      int k0 = (sb_k + it * 2) * 8;
      float f[8];
#pragma unroll
      for (int rr = 0; rr < 8; ++rr)
        f[rr] = Wp[(size_t)(k0g + k0 + rr) * TWO_D + n0 + sb_n];
      bf16x8 pv = { (short)f2bf(f[0]), (short)f2bf(f[1]), (short)f2bf(f[2]), (short)f2bf(f[3]),
                    (short)f2bf(f[4]), (short)f2bf(f[5]), (short)f2bf(f[6]), (short)f2bf(f[7]) };
      *(bf16x8*)(&lB[sb_n * LDSS + k0]) = pv;
    }

    __syncthreads();

    const unsigned short* pA = &lA[(wm * 64 + r) * LDSS + q * 8];
    const unsigned short* pB = &lB[(wn * 64 + r) * LDSS + q * 8];
    bf16x8 af[4], bfr[4];
#pragma unroll
    for (int i = 0; i < 4; ++i) af[i]  = *(const bf16x8*)(pA + i * 16 * LDSS);
#pragma unroll
    for (int j = 0; j < 4; ++j) bfr[j] = *(const bf16x8*)(pB + j * 16 * LDSS);
#pragma unroll
    for (int i = 0; i < 4; ++i)
#pragma unroll
      for (int j = 0; j < 4; ++j)
        acc[i][j] = __builtin_amdgcn_mfma_f32_16x16x32_bf16(af[i], bfr[j], acc[i][j], 0, 0, 0);

    __syncthreads();
  }

  // ---- epilogue: bias, pair gate/up via shfl_xor(1), activation, rw scale, bf16 store
  const float* bp = B1 + (size_t)e * TWO_D;
#pragma unroll
  for (int i = 0; i < 4; ++i) {
    const int mb = m0 + wm * 64 + i * 16 + q * 4;
    float rwv[4];
#pragma unroll
    for (int p = 0; p < 4; ++p) rwv[p] = RW[(mb + p) * NE + e];
#pragma unroll
    for (int j = 0; j < 4; ++j) {
      const int c = n0 + wn * 64 + j * 16 + r;   // global weight column
      const float bias = bp[c];
#pragma unroll
      for (int p = 0; p < 4; ++p) {
        float v = acc[i][j][p] + bias;
        float o = __shfl_xor(v, 1, 64);          // partner column
        float gate = (r & 1) ? o : v;
        float up   = (r & 1) ? v : o;
        gate = fminf(gate, LIMIT);
        up   = fminf(fmaxf(up, -LIMIT), LIMIT);
        float glu = gate / (1.f + __expf(-ALPHA * gate));
        float a   = (up + 1.f) * glu * rwv[p];
        if ((r & 1) == 0) {
          int d = c >> 1;
          A[(size_t)e * T * DDIM + (size_t)(mb + p) * DDIM + d] = f2bf(a);
        }
      }
    }
  }
}

// ---------------------------------------------------------------------------
// GEMM2: per-expert partial (A'[e] @ W2[e]) atomically added into Y.
// grid (8 m, 23 n, 8 e), block 256, tile 128x128x32. rw already folded into A'.
__global__ __launch_bounds__(256) void gemm2_acc_kernel(
    const unsigned short* __restrict__ A, // (E,T,D) bf16
    const float* __restrict__ W2,         // (E,D,H)
    float* __restrict__ Y)                // (T,H) fp32
{
  __shared__ __align__(16) unsigned short lA[128 * LDSS];
  __shared__ __align__(16) unsigned short lB[128 * LDSS];

  const int tid = threadIdx.x;
  const int m0 = blockIdx.x * 128;
  const int n0 = blockIdx.y * 128;
  const int e  = blockIdx.z;
  const float* Wp = W2 + (size_t)e * DDIM * HDIM;
  const unsigned short* Ap = A + (size_t)e * T * DDIM;

  f32x4 acc[4][4];
#pragma unroll
  for (int i = 0; i < 4; ++i)
#pragma unroll
    for (int j = 0; j < 4; ++j) acc[i][j] = (f32x4)0.f;

  const int w    = tid >> 6;
  const int lane = tid & 63;
  const int wm   = w & 1, wn = w >> 1;
  const int r    = lane & 15, q = lane >> 4;

  const int sa_m = tid >> 2;   // 0..63 (x2 iters)
  const int sa_c = tid & 3;    // k-chunk of 8
  const int sb_n = tid & 127;
  const int sb_k = tid >> 7;

  for (int kt = 0; kt < DDIM / 32; ++kt) {
    const int k0g = kt * 32;

    // ---- stage A (already bf16, k-contiguous): straight 16B copies
#pragma unroll
    for (int it = 0; it < 2; ++it) {
      int m = sa_m + it * 64;
      bf16x8 v = *(const bf16x8*)(Ap + (size_t)(m0 + m) * DDIM + k0g + sa_c * 8);
      *(bf16x8*)(&lA[m * LDSS + sa_c * 8]) = v;
    }

    // ---- stage B (W2 fp32, K-major) -> LDS [n][k], bf16; clamp ragged last tile
    int col = n0 + sb_n;
    if (col > HDIM - 1) col = HDIM - 1;
#pragma unroll
    for (int it = 0; it < 2; ++it) {
      int k0 = (sb_k + it * 2) * 8;
      float f[8];
#pragma unroll
      for (int rr = 0; rr < 8; ++rr)
        f[rr] = Wp[(size_t)(k0g + k0 + rr) * HDIM + col];
      bf16x8 pv = { (short)f2bf(f[0]), (short)f2bf(f[1]), (short)f2bf(f[2]), (short)f2bf(f[3]),
                    (short)f2bf(f[4]), (short)f2bf(f[5]), (short)f2bf(f[6]), (short)f2bf(f[7]) };
      *(bf16x8*)(&lB[sb_n * LDSS + k0]) = pv;
    }

    __syncthreads();

    const unsigned short* pA = &lA[(wm * 64 + r) * LDSS + q * 8];
    const unsigned short* pB = &lB[(wn * 64 + r) * LDSS + q * 8];
    bf16x8 af[4], bfr[4];
#pragma unroll
    for (int i = 0; i < 4; ++i) af[i]  = *(const bf16x8*)(pA + i * 16 * LDSS);
#pragma unroll
    for (int j = 0; j < 4; ++j) bfr[j] = *(const bf16x8*)(pB + j * 16 * LDSS);
#pragma unroll
    for (int i = 0; i < 4; ++i)
#pragma unroll
      for (int j = 0; j < 4; ++j)
        acc[i][j] = __builtin_amdgcn_mfma_f32_16x16x32_bf16(af[i], bfr[j], acc[i][j], 0, 0, 0);

    __syncthreads();
  }

  // ---- epilogue: atomic accumulation of expert partial into Y
#pragma unroll
  for (int i = 0; i < 4; ++i) {
    const int mb = m0 + wm * 64 + i * 16 + q * 4;
#pragma unroll
    for (int j = 0; j < 4; ++j) {
      const int h = n0 + wn * 64 + j * 16 + r;
      if (h < HDIM) {
#pragma unroll
        for (int p = 0; p < 4; ++p)
          atomicAdd(&Y[(size_t)(mb + p) * HDIM + h], acc[i][j][p]);
      }
    }
  }
}

// ---------------------------------------------------------------------------
extern "C" void kernel_launch(void* const* d_in, const int* in_sizes, int n_in,
                              void* d_out, int out_size, void* d_ws, size_t ws_size,
                              hipStream_t stream) {
  const float* X  = (const float*)d_in[0];  // hidden_states (1,1024,2880)
  const float* RW = (const float*)d_in[1];  // routing_weights (1024,8)
  const float* W1 = (const float*)d_in[2];  // gate_up_proj (8,2880,5760)
  const float* B1 = (const float*)d_in[3];  // gate_up_proj_bias (8,5760)
  const float* W2 = (const float*)d_in[4];  // down_proj (8,2880,2880)
  const float* B2 = (const float*)d_in[5];  // down_proj_bias (8,2880)
  float* Y = (float*)d_out;                 // (1024,2880) fp32
  unsigned short* Abuf = (unsigned short*)d_ws;  // A' (8,1024,2880) bf16 = 45 MiB

  hipLaunchKernelGGL(init_bias_kernel, dim3(45, 1024), dim3(64), 0, stream, RW, B2, Y);
  hipLaunchKernelGGL(gemm1_act_kernel, dim3(8, 45, 8), dim3(256), 0, stream, X, W1, B1, RW, Abuf);
  hipLaunchKernelGGL(gemm2_acc_kernel, dim3(8, 23, 8), dim3(256), 0, stream, Abuf, W2, Y);
}